// Round 6
// baseline (81.742 us; speedup 1.0000x reference)
//
#include <hip/hip_runtime.h>

// Two-kernel 3x3 neighborhood-attention.
//  K1 coef_kernel: block = 4 waves over the SAME 64 consecutive pixels; wave w
//    accumulates {sr,dot[9],ss[9]} over its 16 channels with fully row-coalesced
//    loads (64 consecutive floats = 2 cache lines per instr), LDS 4-way reduce,
//    wave 0 softmax + 9 coalesced coef-plane stores (patch l2norm folded in).
//  K2 apply_kernel: float4 streaming: out = exp(-(nbr-ref)^2) * sum_k coef_k*nbr_k,
//    x-margins via __shfl (one wave = one full row). Proven ~fast in R2.
// Shapes: [b=2, c=64, h=256, w=256] fp32.

constexpr int C = 64, H = 256, W = 256, HW = H * W;
constexpr int B = 2, PIX = B * HW;
constexpr int SEG = 64;   // pixels per block (one 64-px x segment)
constexpr int NW  = 4;    // waves per block = channel quarters
constexpr int CG  = 16;   // channels per wave

// ---------------- K1: coefficient kernel ----------------
__global__ __launch_bounds__(256) void coef_kernel(const float* __restrict__ nbr,
                                                   const float* __restrict__ ref,
                                                   float* __restrict__ coef) {
  __shared__ float part[19][NW][SEG];

  const int tid  = threadIdx.x;
  const int lane = tid & 63;
  const int w    = tid >> 6;                 // channel quarter 0..3

  const int pix = blockIdx.x * SEG + lane;   // b*HW + y*W + x (segment within one row)
  const int b   = pix >> 16;
  const int p   = pix & (HW - 1);
  const int y   = p >> 8;
  const int x   = p & (W - 1);

  // reflect padding (jnp 'reflect': -1 -> 1, H -> H-2)
  const int ym = (y == 0)     ? 1     : y - 1;
  const int yp = (y == H - 1) ? H - 2 : y + 1;
  const int xm = (x == 0)     ? 1     : x - 1;
  const int xp = (x == W - 1) ? W - 2 : x + 1;

  int off[9];
  off[0] = ym * W + xm; off[1] = ym * W + x; off[2] = ym * W + xp;
  off[3] = y  * W + xm; off[4] = y  * W + x; off[5] = y  * W + xp;
  off[6] = yp * W + xm; off[7] = yp * W + x; off[8] = yp * W + xp;
  const int ctr = y * W + x;

  const float* nb = nbr + ((size_t)b * C + w * CG) * HW;
  const float* rb = ref + ((size_t)b * C + w * CG) * HW;

  float sr = 0.f;
  float dot[9], ss[9];
#pragma unroll
  for (int k = 0; k < 9; ++k) { dot[k] = 0.f; ss[k] = 0.f; }

#pragma unroll 4
  for (int j = 0; j < CG; ++j) {
    const float r = rb[j * HW + ctr];
    sr = fmaf(r, r, sr);
#pragma unroll
    for (int k = 0; k < 9; ++k) {
      const float v = nb[j * HW + off[k]];   // 64 consecutive floats per instr
      dot[k] = fmaf(r, v, dot[k]);
      ss[k]  = fmaf(v, v, ss[k]);
    }
  }

  part[0][w][lane] = sr;
#pragma unroll
  for (int k = 0; k < 9; ++k) {
    part[1 + k][w][lane]  = dot[k];
    part[10 + k][w][lane] = ss[k];
  }
  __syncthreads();

  if (w == 0) {
    const float tsr = part[0][0][lane] + part[0][1][lane] + part[0][2][lane] + part[0][3][lane];
    float td[9], tss[9];
#pragma unroll
    for (int k = 0; k < 9; ++k) {
      td[k]  = part[1 + k][0][lane] + part[1 + k][1][lane] + part[1 + k][2][lane] + part[1 + k][3][lane];
      tss[k] = part[10 + k][0][lane] + part[10 + k][1][lane] + part[10 + k][2][lane] + part[10 + k][3][lane];
    }
    // normalize + softmax over 9 neighbors (sums of 64 squares -> rsqrt safe)
    const float invr = __frsqrt_rn(fmaxf(tsr, 1e-24f));
    float d[9], invp[9];
    float mx = -INFINITY;
#pragma unroll
    for (int k = 0; k < 9; ++k) {
      invp[k] = __frsqrt_rn(fmaxf(tss[k], 1e-24f));
      d[k]    = td[k] * invr * invp[k];
      mx      = fmaxf(mx, d[k]);
    }
    float s = 0.f;
    float cf[9];
#pragma unroll
    for (int k = 0; k < 9; ++k) {
      const float e = __expf(d[k] - mx);
      cf[k] = e;
      s += e;
    }
    const float sinv = 1.0f / s;
#pragma unroll
    for (int k = 0; k < 9; ++k) coef[k * PIX + pix] = cf[k] * sinv * invp[k];
  }
}

// ---------------- K2: apply kernel ----------------
// Thread = 4 consecutive x pixels (quad) x 2 channels. One wave = one full row.
__global__ __launch_bounds__(256) void apply_kernel(const float* __restrict__ nbr,
                                                    const float* __restrict__ ref,
                                                    const float* __restrict__ coef,
                                                    float* __restrict__ out) {
  const int gid  = blockIdx.x * 256 + threadIdx.x;
  const int lane = gid & 63;                 // quad index in row; x0 = lane*4
  const int x0   = lane * 4;
  const int t    = gid >> 6;                 // (b, cpair, y)
  const int y    = t & 255;
  const int u    = t >> 8;                   // 0..63
  const int b    = u >> 5;
  const int c0   = (u & 31) * 2;

  const int ym = (y == 0)     ? 1     : y - 1;
  const int yp = (y == H - 1) ? H - 2 : y + 1;

  const float* n0  = nbr + ((size_t)b * C + c0) * HW;
  const float* n1  = n0 + HW;
  const float* r0p = ref + ((size_t)b * C + c0) * HW;
  float*       o0  = out + ((size_t)b * C + c0) * HW;

  const float4 a0 = *(const float4*)(n0 + ym * W + x0);
  const float4 a1 = *(const float4*)(n0 + y  * W + x0);
  const float4 a2 = *(const float4*)(n0 + yp * W + x0);
  const float4 b0 = *(const float4*)(n1 + ym * W + x0);
  const float4 b1 = *(const float4*)(n1 + y  * W + x0);
  const float4 b2 = *(const float4*)(n1 + yp * W + x0);
  const float4 f0 = *(const float4*)(r0p + y * W + x0);
  const float4 f1 = *(const float4*)(r0p + HW + y * W + x0);

  // x margins via shuffle; reflect at image edges resolves to own elements
  float La0 = __shfl(a0.w, lane - 1), Ra0 = __shfl(a0.x, lane + 1);
  float La1 = __shfl(a1.w, lane - 1), Ra1 = __shfl(a1.x, lane + 1);
  float La2 = __shfl(a2.w, lane - 1), Ra2 = __shfl(a2.x, lane + 1);
  float Lb0 = __shfl(b0.w, lane - 1), Rb0 = __shfl(b0.x, lane + 1);
  float Lb1 = __shfl(b1.w, lane - 1), Rb1 = __shfl(b1.x, lane + 1);
  float Lb2 = __shfl(b2.w, lane - 1), Rb2 = __shfl(b2.x, lane + 1);
  if (lane == 0)  { La0 = a0.y; La1 = a1.y; La2 = a2.y; Lb0 = b0.y; Lb1 = b1.y; Lb2 = b2.y; }
  if (lane == 63) { Ra0 = a0.z; Ra1 = a1.z; Ra2 = a2.z; Rb0 = b0.z; Rb1 = b1.z; Rb2 = b2.z; }

  float va[3][6] = {{La0, a0.x, a0.y, a0.z, a0.w, Ra0},
                    {La1, a1.x, a1.y, a1.z, a1.w, Ra1},
                    {La2, a2.x, a2.y, a2.z, a2.w, Ra2}};
  float vb[3][6] = {{Lb0, b0.x, b0.y, b0.z, b0.w, Rb0},
                    {Lb1, b1.x, b1.y, b1.z, b1.w, Rb1},
                    {Lb2, b2.x, b2.y, b2.z, b2.w, Rb2}};

  const int cbase = b * HW + y * W + x0;
  float aga[4] = {0.f, 0.f, 0.f, 0.f};
  float agb[4] = {0.f, 0.f, 0.f, 0.f};
#pragma unroll
  for (int k = 0; k < 9; ++k) {
    const float4 cf = *(const float4*)(coef + k * PIX + cbase);
    const int r  = k / 3;
    const int cx = k % 3;
    const float cfe[4] = {cf.x, cf.y, cf.z, cf.w};
#pragma unroll
    for (int e = 0; e < 4; ++e) {
      aga[e] = fmaf(cfe[e], va[r][e + cx], aga[e]);
      agb[e] = fmaf(cfe[e], vb[r][e + cx], agb[e]);
    }
  }

  const float ctra[4] = {a1.x, a1.y, a1.z, a1.w};
  const float ctrb[4] = {b1.x, b1.y, b1.z, b1.w};
  const float rfa[4]  = {f0.x, f0.y, f0.z, f0.w};
  const float rfb[4]  = {f1.x, f1.y, f1.z, f1.w};
  float oae[4], obe[4];
#pragma unroll
  for (int e = 0; e < 4; ++e) {
    const float da = ctra[e] - rfa[e];
    const float db = ctrb[e] - rfb[e];
    oae[e] = aga[e] * __expf(-(da * da));
    obe[e] = agb[e] * __expf(-(db * db));
  }
  float4 oa, ob4;
  oa.x = oae[0]; oa.y = oae[1]; oa.z = oae[2]; oa.w = oae[3];
  ob4.x = obe[0]; ob4.y = obe[1]; ob4.z = obe[2]; ob4.w = obe[3];

  *(float4*)(o0 + y * W + x0) = oa;
  *(float4*)(o0 + HW + y * W + x0) = ob4;
}

// ---------------- fallback: R4 fused kernel (if ws too small) ----------------
__global__ __launch_bounds__(256) void fused_nbr_attn(const float* __restrict__ nbr,
                                                      const float* __restrict__ ref,
                                                      float* __restrict__ out) {
  const int tid  = threadIdx.x;
  const int lane = tid & 63;
  const int wv   = tid >> 6;
  const int px   = lane & 7;
  const int cg   = lane >> 3;

  const int pix = blockIdx.x * 32 + wv * 8 + px;
  const int b   = pix >> 16;
  const int p   = pix & (HW - 1);
  const int y   = p >> 8;
  const int x   = p & (W - 1);

  const int ym = (y == 0)     ? 1     : y - 1;
  const int yp = (y == H - 1) ? H - 2 : y + 1;
  const int xm = (x == 0)     ? 1     : x - 1;
  const int xp = (x == W - 1) ? W - 2 : x + 1;

  int off[9];
  off[0] = ym * W + xm; off[1] = ym * W + x; off[2] = ym * W + xp;
  off[3] = y  * W + xm; off[4] = y  * W + x; off[5] = y  * W + xp;
  off[6] = yp * W + xm; off[7] = yp * W + x; off[8] = yp * W + xp;
  const int ctr = y * W + x;

  const float* nb = nbr + ((size_t)b * C + cg * 8) * HW;
  const float* rb = ref + ((size_t)b * C + cg * 8) * HW;
  float*       ob = out + ((size_t)b * C + cg * 8) * HW;

  float v[8][9], r[8];
#pragma unroll
  for (int j = 0; j < 8; ++j) {
    r[j] = rb[j * HW + ctr];
#pragma unroll
    for (int k = 0; k < 9; ++k) v[j][k] = nb[j * HW + off[k]];
  }
  float sr = 0.f;
  float dot[9], ss[9];
#pragma unroll
  for (int k = 0; k < 9; ++k) { dot[k] = 0.f; ss[k] = 0.f; }
#pragma unroll
  for (int j = 0; j < 8; ++j) {
    sr = fmaf(r[j], r[j], sr);
#pragma unroll
    for (int k = 0; k < 9; ++k) {
      dot[k] = fmaf(r[j], v[j][k], dot[k]);
      ss[k]  = fmaf(v[j][k], v[j][k], ss[k]);
    }
  }
#pragma unroll
  for (int m = 8; m < 64; m <<= 1) {
    sr += __shfl_xor(sr, m);
#pragma unroll
    for (int k = 0; k < 9; ++k) {
      dot[k] += __shfl_xor(dot[k], m);
      ss[k]  += __shfl_xor(ss[k], m);
    }
  }
  const float invr = __frsqrt_rn(fmaxf(sr, 1e-24f));
  float d[9], invp[9];
  float mx = -INFINITY;
#pragma unroll
  for (int k = 0; k < 9; ++k) {
    invp[k] = __frsqrt_rn(fmaxf(ss[k], 1e-24f));
    d[k]    = dot[k] * invr * invp[k];
    mx      = fmaxf(mx, d[k]);
  }
  float s = 0.f;
  float coef[9];
#pragma unroll
  for (int k = 0; k < 9; ++k) {
    const float e = __expf(d[k] - mx);
    coef[k] = e;
    s += e;
  }
  const float sinv = 1.0f / s;
#pragma unroll
  for (int k = 0; k < 9; ++k) coef[k] *= sinv * invp[k];
#pragma unroll
  for (int j = 0; j < 8; ++j) {
    float a = 0.f;
#pragma unroll
    for (int k = 0; k < 9; ++k) a = fmaf(coef[k], v[j][k], a);
    const float diff = v[j][4] - r[j];
    const float wd   = __expf(-(diff * diff));
    ob[j * HW + ctr] = a * wd;
  }
}

extern "C" void kernel_launch(void* const* d_in, const int* in_sizes, int n_in,
                              void* d_out, int out_size, void* d_ws, size_t ws_size,
                              hipStream_t stream) {
  const float* nbr = (const float*)d_in[0];
  const float* ref = (const float*)d_in[1];
  float*       out = (float*)d_out;
  const size_t coef_bytes = (size_t)9 * PIX * sizeof(float);

  if (ws_size >= coef_bytes) {
    float* coef = (float*)d_ws;
    coef_kernel<<<dim3(PIX / SEG), dim3(256), 0, stream>>>(nbr, ref, coef);
    apply_kernel<<<dim3(PIX / 4 * (C / 2) / 256), dim3(256), 0, stream>>>(nbr, ref, coef, out);
  } else {
    fused_nbr_attn<<<dim3(PIX / 32), dim3(256), 0, stream>>>(nbr, ref, out);
  }
}

// Round 7
// 53.231 us; speedup vs baseline: 1.5356x; 1.5356x over previous
//
#include <hip/hip_runtime.h>

// Two-kernel 3x3 neighborhood-attention.
//  K1 coef_kernel: thread = 2 adjacent px x 16 channels; 4 lane-groups (cg)
//    per pixel-pair -> butterfly reduce (xor 16/32). Per channel-row the
//    4-value window [x-1..x+2] = 3 aligned float2 loads at {max(x0-2,0), x0,
//    min(x0+2,254)} -- clamping reproduces reflect padding exactly, no selects.
//    Loads staged into q[4][10] register batches (40 independent VMEM per
//    batch) decoupled from the FMA consumption to beat vmcnt(0) serialization.
//  K2 apply_kernel: float4 streaming out = exp(-(nbr-ref)^2)*sum_k coef_k*nbr_k.
// Shapes: [b=2, c=64, h=256, w=256] fp32.

constexpr int C = 64, H = 256, W = 256, HW = H * W;
constexpr int B = 2, PIX = B * HW;

__device__ __forceinline__ float2 ld2(const float* p) { return *(const float2*)p; }

// ---------------- K1: coefficient kernel ----------------
__global__ __launch_bounds__(256) void coef_kernel(const float* __restrict__ nbr,
                                                   const float* __restrict__ ref,
                                                   float* __restrict__ coef) {
  const int tid  = threadIdx.x;
  const int lane = tid & 63;
  const int wv   = tid >> 6;
  const int pr   = lane & 15;        // pixel-pair slot: 16 pairs = 32 px per wave
  const int cg   = lane >> 4;        // channel group 0..3 (16 ch each)

  const int gw   = blockIdx.x * 4 + wv;     // global wave id, 0..4095
  const int pix0 = gw * 32 + pr * 2;        // even pixel index; pair = {pix0, pix0+1}
  const int b    = pix0 >> 16;
  const int p    = pix0 & (HW - 1);
  const int y    = p >> 8;
  const int x0   = p & (W - 1);             // even, 0..254

  // reflect rows (jnp 'reflect': -1 -> 1, H -> H-2)
  const int ym = (y == 0)     ? 1     : y - 1;
  const int yp = (y == H - 1) ? H - 2 : y + 1;
  const int oM = ym * W, oC = y * W, oP = yp * W;

  // x-window clamps: reflect handled exactly (x0=0 -> .y=1; x0=254 -> .x=254)
  const int aL = (x0 == 0)     ? 0   : x0 - 2;
  const int aR = (x0 == W - 2) ? 254 : x0 + 2;

  const float* nb = nbr + ((size_t)b * C + cg * 16) * HW;
  const float* rb = ref + ((size_t)b * C + cg * 16) * HW;

  float sr0 = 0.f, sr1 = 0.f;
  float dot0[9], ss0[9], dot1[9], ss1[9];
#pragma unroll
  for (int k = 0; k < 9; ++k) { dot0[k] = ss0[k] = dot1[k] = ss1[k] = 0.f; }

#pragma unroll 1
  for (int jc = 0; jc < 16; jc += 4) {
    float2 q[4][10];
#pragma unroll
    for (int u = 0; u < 4; ++u) {
      const float* pl = nb + (size_t)(jc + u) * HW;
      q[u][0] = ld2(pl + oM + aL); q[u][1] = ld2(pl + oM + x0); q[u][2] = ld2(pl + oM + aR);
      q[u][3] = ld2(pl + oC + aL); q[u][4] = ld2(pl + oC + x0); q[u][5] = ld2(pl + oC + aR);
      q[u][6] = ld2(pl + oP + aL); q[u][7] = ld2(pl + oP + x0); q[u][8] = ld2(pl + oP + aR);
      q[u][9] = ld2(rb + (size_t)(jc + u) * HW + oC + x0);
    }
#pragma unroll
    for (int u = 0; u < 4; ++u) {
      const float r0 = q[u][9].x, r1 = q[u][9].y;
      sr0 = fmaf(r0, r0, sr0);
      sr1 = fmaf(r1, r1, sr1);
#pragma unroll
      for (int rr = 0; rr < 3; ++rr) {
        const float2 L = q[u][rr * 3 + 0];
        const float2 Cm = q[u][rr * 3 + 1];
        const float2 R = q[u][rr * 3 + 2];
        const int k = rr * 3;
        // px0 (x=x0): neighbors (L.y, Cm.x, Cm.y); px1 (x=x0+1): (Cm.x, Cm.y, R.x)
        const float sLy = L.y * L.y, sCx = Cm.x * Cm.x, sCy = Cm.y * Cm.y, sRx = R.x * R.x;
        dot0[k + 0] = fmaf(r0, L.y,  dot0[k + 0]); ss0[k + 0] += sLy;
        dot0[k + 1] = fmaf(r0, Cm.x, dot0[k + 1]); ss0[k + 1] += sCx;
        dot0[k + 2] = fmaf(r0, Cm.y, dot0[k + 2]); ss0[k + 2] += sCy;
        dot1[k + 0] = fmaf(r1, Cm.x, dot1[k + 0]); ss1[k + 0] += sCx;
        dot1[k + 1] = fmaf(r1, Cm.y, dot1[k + 1]); ss1[k + 1] += sCy;
        dot1[k + 2] = fmaf(r1, R.x,  dot1[k + 2]); ss1[k + 2] += sRx;
      }
    }
  }

  // ---- butterfly reduce the 4 cg lane-groups (xor 16, 32) ----
#pragma unroll
  for (int m = 16; m < 64; m <<= 1) {
    sr0 += __shfl_xor(sr0, m);
    sr1 += __shfl_xor(sr1, m);
#pragma unroll
    for (int k = 0; k < 9; ++k) {
      dot0[k] += __shfl_xor(dot0[k], m);
      ss0[k]  += __shfl_xor(ss0[k], m);
      dot1[k] += __shfl_xor(dot1[k], m);
      ss1[k]  += __shfl_xor(ss1[k], m);
    }
  }

  // ---- normalize + softmax for both pixels (redundant across cg lanes) ----
  const float invr0 = __frsqrt_rn(fmaxf(sr0, 1e-24f));
  const float invr1 = __frsqrt_rn(fmaxf(sr1, 1e-24f));
  float d0[9], d1[9], ip0[9], ip1[9];
  float mx0 = -INFINITY, mx1 = -INFINITY;
#pragma unroll
  for (int k = 0; k < 9; ++k) {
    ip0[k] = __frsqrt_rn(fmaxf(ss0[k], 1e-24f));
    ip1[k] = __frsqrt_rn(fmaxf(ss1[k], 1e-24f));
    d0[k]  = dot0[k] * invr0 * ip0[k];
    d1[k]  = dot1[k] * invr1 * ip1[k];
    mx0 = fmaxf(mx0, d0[k]);
    mx1 = fmaxf(mx1, d1[k]);
  }
  float s0 = 0.f, s1 = 0.f;
  float c0[9], c1[9];
#pragma unroll
  for (int k = 0; k < 9; ++k) {
    c0[k] = __expf(d0[k] - mx0); s0 += c0[k];
    c1[k] = __expf(d1[k] - mx1); s1 += c1[k];
  }
  const float si0 = 1.0f / s0, si1 = 1.0f / s1;

  if (cg == 0) {
#pragma unroll
    for (int k = 0; k < 9; ++k) {
      float2 cf;
      cf.x = c0[k] * si0 * ip0[k];   // patch l2norm folded in
      cf.y = c1[k] * si1 * ip1[k];
      *(float2*)(coef + (size_t)k * PIX + pix0) = cf;
    }
  }
}

// ---------------- K2: apply kernel (unchanged from R5) ----------------
__global__ __launch_bounds__(256) void apply_kernel(const float* __restrict__ nbr,
                                                    const float* __restrict__ ref,
                                                    const float* __restrict__ coef,
                                                    float* __restrict__ out) {
  const int gid  = blockIdx.x * 256 + threadIdx.x;
  const int lane = gid & 63;
  const int x0   = lane * 4;
  const int t    = gid >> 6;
  const int y    = t & 255;
  const int u    = t >> 8;
  const int b    = u >> 5;
  const int c0   = (u & 31) * 2;

  const int ym = (y == 0)     ? 1     : y - 1;
  const int yp = (y == H - 1) ? H - 2 : y + 1;

  const float* n0  = nbr + ((size_t)b * C + c0) * HW;
  const float* n1  = n0 + HW;
  const float* r0p = ref + ((size_t)b * C + c0) * HW;
  float*       o0  = out + ((size_t)b * C + c0) * HW;

  const float4 a0 = *(const float4*)(n0 + ym * W + x0);
  const float4 a1 = *(const float4*)(n0 + y  * W + x0);
  const float4 a2 = *(const float4*)(n0 + yp * W + x0);
  const float4 b0 = *(const float4*)(n1 + ym * W + x0);
  const float4 b1 = *(const float4*)(n1 + y  * W + x0);
  const float4 b2 = *(const float4*)(n1 + yp * W + x0);
  const float4 f0 = *(const float4*)(r0p + y * W + x0);
  const float4 f1 = *(const float4*)(r0p + HW + y * W + x0);

  float La0 = __shfl(a0.w, lane - 1), Ra0 = __shfl(a0.x, lane + 1);
  float La1 = __shfl(a1.w, lane - 1), Ra1 = __shfl(a1.x, lane + 1);
  float La2 = __shfl(a2.w, lane - 1), Ra2 = __shfl(a2.x, lane + 1);
  float Lb0 = __shfl(b0.w, lane - 1), Rb0 = __shfl(b0.x, lane + 1);
  float Lb1 = __shfl(b1.w, lane - 1), Rb1 = __shfl(b1.x, lane + 1);
  float Lb2 = __shfl(b2.w, lane - 1), Rb2 = __shfl(b2.x, lane + 1);
  if (lane == 0)  { La0 = a0.y; La1 = a1.y; La2 = a2.y; Lb0 = b0.y; Lb1 = b1.y; Lb2 = b2.y; }
  if (lane == 63) { Ra0 = a0.z; Ra1 = a1.z; Ra2 = a2.z; Rb0 = b0.z; Rb1 = b1.z; Rb2 = b2.z; }

  float va[3][6] = {{La0, a0.x, a0.y, a0.z, a0.w, Ra0},
                    {La1, a1.x, a1.y, a1.z, a1.w, Ra1},
                    {La2, a2.x, a2.y, a2.z, a2.w, Ra2}};
  float vb[3][6] = {{Lb0, b0.x, b0.y, b0.z, b0.w, Rb0},
                    {Lb1, b1.x, b1.y, b1.z, b1.w, Rb1},
                    {Lb2, b2.x, b2.y, b2.z, b2.w, Rb2}};

  const int cbase = b * HW + y * W + x0;
  float aga[4] = {0.f, 0.f, 0.f, 0.f};
  float agb[4] = {0.f, 0.f, 0.f, 0.f};
#pragma unroll
  for (int k = 0; k < 9; ++k) {
    const float4 cf = *(const float4*)(coef + (size_t)k * PIX + cbase);
    const int r  = k / 3;
    const int cx = k % 3;
    const float cfe[4] = {cf.x, cf.y, cf.z, cf.w};
#pragma unroll
    for (int e = 0; e < 4; ++e) {
      aga[e] = fmaf(cfe[e], va[r][e + cx], aga[e]);
      agb[e] = fmaf(cfe[e], vb[r][e + cx], agb[e]);
    }
  }

  const float ctra[4] = {a1.x, a1.y, a1.z, a1.w};
  const float ctrb[4] = {b1.x, b1.y, b1.z, b1.w};
  const float rfa[4]  = {f0.x, f0.y, f0.z, f0.w};
  const float rfb[4]  = {f1.x, f1.y, f1.z, f1.w};
  float oae[4], obe[4];
#pragma unroll
  for (int e = 0; e < 4; ++e) {
    const float da = ctra[e] - rfa[e];
    const float db = ctrb[e] - rfb[e];
    oae[e] = aga[e] * __expf(-(da * da));
    obe[e] = agb[e] * __expf(-(db * db));
  }
  float4 oa, ob4;
  oa.x = oae[0]; oa.y = oae[1]; oa.z = oae[2]; oa.w = oae[3];
  ob4.x = obe[0]; ob4.y = obe[1]; ob4.z = obe[2]; ob4.w = obe[3];

  *(float4*)(o0 + y * W + x0) = oa;
  *(float4*)(o0 + HW + y * W + x0) = ob4;
}

// ---------------- fallback: R4 fused kernel (if ws too small) ----------------
__global__ __launch_bounds__(256) void fused_nbr_attn(const float* __restrict__ nbr,
                                                      const float* __restrict__ ref,
                                                      float* __restrict__ out) {
  const int tid  = threadIdx.x;
  const int lane = tid & 63;
  const int wv   = tid >> 6;
  const int px   = lane & 7;
  const int cg   = lane >> 3;

  const int pix = blockIdx.x * 32 + wv * 8 + px;
  const int b   = pix >> 16;
  const int p   = pix & (HW - 1);
  const int y   = p >> 8;
  const int x   = p & (W - 1);

  const int ym = (y == 0)     ? 1     : y - 1;
  const int yp = (y == H - 1) ? H - 2 : y + 1;
  const int xm = (x == 0)     ? 1     : x - 1;
  const int xp = (x == W - 1) ? W - 2 : x + 1;

  int off[9];
  off[0] = ym * W + xm; off[1] = ym * W + x; off[2] = ym * W + xp;
  off[3] = y  * W + xm; off[4] = y  * W + x; off[5] = y  * W + xp;
  off[6] = yp * W + xm; off[7] = yp * W + x; off[8] = yp * W + xp;
  const int ctr = y * W + x;

  const float* nb = nbr + ((size_t)b * C + cg * 8) * HW;
  const float* rb = ref + ((size_t)b * C + cg * 8) * HW;
  float*       ob = out + ((size_t)b * C + cg * 8) * HW;

  float v[8][9], r[8];
#pragma unroll
  for (int j = 0; j < 8; ++j) {
    r[j] = rb[j * HW + ctr];
#pragma unroll
    for (int k = 0; k < 9; ++k) v[j][k] = nb[j * HW + off[k]];
  }
  float sr = 0.f;
  float dot[9], ss[9];
#pragma unroll
  for (int k = 0; k < 9; ++k) { dot[k] = 0.f; ss[k] = 0.f; }
#pragma unroll
  for (int j = 0; j < 8; ++j) {
    sr = fmaf(r[j], r[j], sr);
#pragma unroll
    for (int k = 0; k < 9; ++k) {
      dot[k] = fmaf(r[j], v[j][k], dot[k]);
      ss[k]  = fmaf(v[j][k], v[j][k], ss[k]);
    }
  }
#pragma unroll
  for (int m = 8; m < 64; m <<= 1) {
    sr += __shfl_xor(sr, m);
#pragma unroll
    for (int k = 0; k < 9; ++k) {
      dot[k] += __shfl_xor(dot[k], m);
      ss[k]  += __shfl_xor(ss[k], m);
    }
  }
  const float invr = __frsqrt_rn(fmaxf(sr, 1e-24f));
  float d[9], invp[9];
  float mx = -INFINITY;
#pragma unroll
  for (int k = 0; k < 9; ++k) {
    invp[k] = __frsqrt_rn(fmaxf(ss[k], 1e-24f));
    d[k]    = dot[k] * invr * invp[k];
    mx      = fmaxf(mx, d[k]);
  }
  float s = 0.f;
  float coef[9];
#pragma unroll
  for (int k = 0; k < 9; ++k) {
    const float e = __expf(d[k] - mx);
    coef[k] = e;
    s += e;
  }
  const float sinv = 1.0f / s;
#pragma unroll
  for (int k = 0; k < 9; ++k) coef[k] *= sinv * invp[k];
#pragma unroll
  for (int j = 0; j < 8; ++j) {
    float a = 0.f;
#pragma unroll
    for (int k = 0; k < 9; ++k) a = fmaf(coef[k], v[j][k], a);
    const float diff = v[j][4] - r[j];
    const float wd   = __expf(-(diff * diff));
    ob[j * HW + ctr] = a * wd;
  }
}

extern "C" void kernel_launch(void* const* d_in, const int* in_sizes, int n_in,
                              void* d_out, int out_size, void* d_ws, size_t ws_size,
                              hipStream_t stream) {
  const float* nbr = (const float*)d_in[0];
  const float* ref = (const float*)d_in[1];
  float*       out = (float*)d_out;
  const size_t coef_bytes = (size_t)9 * PIX * sizeof(float);

  if (ws_size >= coef_bytes) {
    float* coef = (float*)d_ws;
    coef_kernel<<<dim3(PIX / 128), dim3(256), 0, stream>>>(nbr, ref, coef);   // 1024 blocks
    apply_kernel<<<dim3(PIX / 4 * (C / 2) / 256), dim3(256), 0, stream>>>(nbr, ref, coef, out);
  } else {
    fused_nbr_attn<<<dim3(PIX / 32), dim3(256), 0, stream>>>(nbr, ref, out);
  }
}

// Round 8
// 45.110 us; speedup vs baseline: 1.8120x; 1.1800x over previous
//
#include <hip/hip_runtime.h>
#include <stdint.h>

// Two-kernel 3x3 neighborhood-attention.
//  K1 coef2_kernel: block = one image row (256 px), thread = 1 px. Channels
//    stream through a double-buffered LDS tile via global_load_lds (16B/lane,
//    one instr per 1KB row, ZERO VGPR cost -> deep async queue the compiler
//    can't strangle). Each thread accumulates sr/dot[9]/ss[9] thread-locally
//    from LDS (no cross-lane reduce), then softmax + coalesced coef stores.
//  K2 apply_kernel: float4 streaming out = exp(-(nbr-ref)^2)*sum_k coef_k*nbr_k.
// Shapes: [b=2, c=64, h=256, w=256] fp32.

constexpr int C = 64, H = 256, W = 256, HW = H * W;
constexpr int B = 2, PIX = B * HW;
constexpr int CHUNK = 8;            // channels per staged chunk
constexpr int NCHUNK = C / CHUNK;   // 8

typedef const __attribute__((address_space(1))) void* gas_ptr;
typedef __attribute__((address_space(3))) void* las_ptr;

// ---------------- K1: coefficient kernel (LDS-staged) ----------------
__global__ __launch_bounds__(256) void coef2_kernel(const float* __restrict__ nbr,
                                                    const float* __restrict__ ref,
                                                    float* __restrict__ coef) {
  // buf[dbuf][ch][row: 0..2 = nbr @ {ym,y,yp}, 3 = ref @ y][W]  = 64 KB
  __shared__ float buf[2][CHUNK][4][W];

  const int tid  = threadIdx.x;
  const int lane = tid & 63;
  const int wv   = tid >> 6;          // wave 0..3

  const int by = blockIdx.x;          // b*256 + y
  const int b  = by >> 8;
  const int y  = by & 255;
  const int ym = (y == 0)     ? 1     : y - 1;   // jnp reflect
  const int yp = (y == H - 1) ? H - 2 : y + 1;

  const float* nbase = nbr + (size_t)b * C * HW;
  const float* rbase = ref + (size_t)b * C * HW;
  const int rowoff0 = ym * W, rowoff1 = y * W, rowoff2 = yp * W;

  // stage chunk -> buf[bi]: wave wv issues 8 loads (2 channels x 4 rows);
  // each global_load_lds: lane l loads 16B at g+l*16 -> LDS base + l*16.
  auto stage = [&](int chunk, int bi) {
#pragma unroll
    for (int u = 0; u < 2; ++u) {
      const int cc = 2 * wv + u;
      const int c  = chunk * CHUNK + cc;
      const float* nrow = nbase + (size_t)c * HW;
      const float* rrow = rbase + (size_t)c * HW;
      __builtin_amdgcn_global_load_lds((gas_ptr)(nrow + rowoff0 + lane * 4),
                                       (las_ptr)&buf[bi][cc][0][0], 16, 0, 0);
      __builtin_amdgcn_global_load_lds((gas_ptr)(nrow + rowoff1 + lane * 4),
                                       (las_ptr)&buf[bi][cc][1][0], 16, 0, 0);
      __builtin_amdgcn_global_load_lds((gas_ptr)(nrow + rowoff2 + lane * 4),
                                       (las_ptr)&buf[bi][cc][2][0], 16, 0, 0);
      __builtin_amdgcn_global_load_lds((gas_ptr)(rrow + rowoff1 + lane * 4),
                                       (las_ptr)&buf[bi][cc][3][0], 16, 0, 0);
    }
  };

  // thread <-> pixel mapping: x = tid (0..255)
  const int x  = tid;
  const int xm = (x == 0)     ? 1     : x - 1;
  const int xp = (x == W - 1) ? W - 2 : x + 1;

  float sr = 0.f;
  float dot[9], ss[9];
#pragma unroll
  for (int k = 0; k < 9; ++k) { dot[k] = 0.f; ss[k] = 0.f; }

  stage(0, 0);
  __syncthreads();   // drains vmcnt -> chunk 0 visible

  for (int i = 0; i < NCHUNK; ++i) {
    const int bi = i & 1;
    if (i + 1 < NCHUNK) stage(i + 1, bi ^ 1);   // prefetch overlaps consume
#pragma unroll
    for (int cc = 0; cc < CHUNK; ++cc) {
      const float r  = buf[bi][cc][3][x];
      const float v0 = buf[bi][cc][0][xm], v1 = buf[bi][cc][0][x], v2 = buf[bi][cc][0][xp];
      const float v3 = buf[bi][cc][1][xm], v4 = buf[bi][cc][1][x], v5 = buf[bi][cc][1][xp];
      const float v6 = buf[bi][cc][2][xm], v7 = buf[bi][cc][2][x], v8 = buf[bi][cc][2][xp];
      sr = fmaf(r, r, sr);
      dot[0] = fmaf(r, v0, dot[0]); ss[0] = fmaf(v0, v0, ss[0]);
      dot[1] = fmaf(r, v1, dot[1]); ss[1] = fmaf(v1, v1, ss[1]);
      dot[2] = fmaf(r, v2, dot[2]); ss[2] = fmaf(v2, v2, ss[2]);
      dot[3] = fmaf(r, v3, dot[3]); ss[3] = fmaf(v3, v3, ss[3]);
      dot[4] = fmaf(r, v4, dot[4]); ss[4] = fmaf(v4, v4, ss[4]);
      dot[5] = fmaf(r, v5, dot[5]); ss[5] = fmaf(v5, v5, ss[5]);
      dot[6] = fmaf(r, v6, dot[6]); ss[6] = fmaf(v6, v6, ss[6]);
      dot[7] = fmaf(r, v7, dot[7]); ss[7] = fmaf(v7, v7, ss[7]);
      dot[8] = fmaf(r, v8, dot[8]); ss[8] = fmaf(v8, v8, ss[8]);
    }
    __syncthreads();   // drains vmcnt (next chunk ready) + protects dbuf reuse
  }

  // ---- normalize + softmax over the 9 neighbors ----
  const float invr = __frsqrt_rn(fmaxf(sr, 1e-24f));
  float d[9], invp[9];
  float mx = -INFINITY;
#pragma unroll
  for (int k = 0; k < 9; ++k) {
    invp[k] = __frsqrt_rn(fmaxf(ss[k], 1e-24f));
    d[k]    = dot[k] * invr * invp[k];
    mx      = fmaxf(mx, d[k]);
  }
  float s = 0.f;
  float cf[9];
#pragma unroll
  for (int k = 0; k < 9; ++k) {
    cf[k] = __expf(d[k] - mx);
    s += cf[k];
  }
  const float sinv = 1.0f / s;

  const int pix = by * W + x;         // b*HW + y*W + x
#pragma unroll
  for (int k = 0; k < 9; ++k)
    coef[(size_t)k * PIX + pix] = cf[k] * sinv * invp[k];   // patch l2norm folded
}

// ---------------- K2: apply kernel (proven; unchanged) ----------------
__global__ __launch_bounds__(256) void apply_kernel(const float* __restrict__ nbr,
                                                    const float* __restrict__ ref,
                                                    const float* __restrict__ coef,
                                                    float* __restrict__ out) {
  const int gid  = blockIdx.x * 256 + threadIdx.x;
  const int lane = gid & 63;
  const int x0   = lane * 4;
  const int t    = gid >> 6;
  const int y    = t & 255;
  const int u    = t >> 8;
  const int b    = u >> 5;
  const int c0   = (u & 31) * 2;

  const int ym = (y == 0)     ? 1     : y - 1;
  const int yp = (y == H - 1) ? H - 2 : y + 1;

  const float* n0  = nbr + ((size_t)b * C + c0) * HW;
  const float* n1  = n0 + HW;
  const float* r0p = ref + ((size_t)b * C + c0) * HW;
  float*       o0  = out + ((size_t)b * C + c0) * HW;

  const float4 a0 = *(const float4*)(n0 + ym * W + x0);
  const float4 a1 = *(const float4*)(n0 + y  * W + x0);
  const float4 a2 = *(const float4*)(n0 + yp * W + x0);
  const float4 b0 = *(const float4*)(n1 + ym * W + x0);
  const float4 b1 = *(const float4*)(n1 + y  * W + x0);
  const float4 b2 = *(const float4*)(n1 + yp * W + x0);
  const float4 f0 = *(const float4*)(r0p + y * W + x0);
  const float4 f1 = *(const float4*)(r0p + HW + y * W + x0);

  float La0 = __shfl(a0.w, lane - 1), Ra0 = __shfl(a0.x, lane + 1);
  float La1 = __shfl(a1.w, lane - 1), Ra1 = __shfl(a1.x, lane + 1);
  float La2 = __shfl(a2.w, lane - 1), Ra2 = __shfl(a2.x, lane + 1);
  float Lb0 = __shfl(b0.w, lane - 1), Rb0 = __shfl(b0.x, lane + 1);
  float Lb1 = __shfl(b1.w, lane - 1), Rb1 = __shfl(b1.x, lane + 1);
  float Lb2 = __shfl(b2.w, lane - 1), Rb2 = __shfl(b2.x, lane + 1);
  if (lane == 0)  { La0 = a0.y; La1 = a1.y; La2 = a2.y; Lb0 = b0.y; Lb1 = b1.y; Lb2 = b2.y; }
  if (lane == 63) { Ra0 = a0.z; Ra1 = a1.z; Ra2 = a2.z; Rb0 = b0.z; Rb1 = b1.z; Rb2 = b2.z; }

  float va[3][6] = {{La0, a0.x, a0.y, a0.z, a0.w, Ra0},
                    {La1, a1.x, a1.y, a1.z, a1.w, Ra1},
                    {La2, a2.x, a2.y, a2.z, a2.w, Ra2}};
  float vb[3][6] = {{Lb0, b0.x, b0.y, b0.z, b0.w, Rb0},
                    {Lb1, b1.x, b1.y, b1.z, b1.w, Rb1},
                    {Lb2, b2.x, b2.y, b2.z, b2.w, Rb2}};

  const int cbase = b * HW + y * W + x0;
  float aga[4] = {0.f, 0.f, 0.f, 0.f};
  float agb[4] = {0.f, 0.f, 0.f, 0.f};
#pragma unroll
  for (int k = 0; k < 9; ++k) {
    const float4 cf = *(const float4*)(coef + (size_t)k * PIX + cbase);
    const int r  = k / 3;
    const int cx = k % 3;
    const float cfe[4] = {cf.x, cf.y, cf.z, cf.w};
#pragma unroll
    for (int e = 0; e < 4; ++e) {
      aga[e] = fmaf(cfe[e], va[r][e + cx], aga[e]);
      agb[e] = fmaf(cfe[e], vb[r][e + cx], agb[e]);
    }
  }

  const float ctra[4] = {a1.x, a1.y, a1.z, a1.w};
  const float ctrb[4] = {b1.x, b1.y, b1.z, b1.w};
  const float rfa[4]  = {f0.x, f0.y, f0.z, f0.w};
  const float rfb[4]  = {f1.x, f1.y, f1.z, f1.w};
  float oae[4], obe[4];
#pragma unroll
  for (int e = 0; e < 4; ++e) {
    const float da = ctra[e] - rfa[e];
    const float db = ctrb[e] - rfb[e];
    oae[e] = aga[e] * __expf(-(da * da));
    obe[e] = agb[e] * __expf(-(db * db));
  }
  float4 oa, ob4;
  oa.x = oae[0]; oa.y = oae[1]; oa.z = oae[2]; oa.w = oae[3];
  ob4.x = obe[0]; ob4.y = obe[1]; ob4.z = obe[2]; ob4.w = obe[3];

  *(float4*)(o0 + y * W + x0) = oa;
  *(float4*)(o0 + HW + y * W + x0) = ob4;
}

// ---------------- fallback: R4 fused kernel (if ws too small) ----------------
__global__ __launch_bounds__(256) void fused_nbr_attn(const float* __restrict__ nbr,
                                                      const float* __restrict__ ref,
                                                      float* __restrict__ out) {
  const int tid  = threadIdx.x;
  const int lane = tid & 63;
  const int wv   = tid >> 6;
  const int px   = lane & 7;
  const int cg   = lane >> 3;

  const int pix = blockIdx.x * 32 + wv * 8 + px;
  const int b   = pix >> 16;
  const int p   = pix & (HW - 1);
  const int y   = p >> 8;
  const int x   = p & (W - 1);

  const int ym = (y == 0)     ? 1     : y - 1;
  const int yp = (y == H - 1) ? H - 2 : y + 1;
  const int xm = (x == 0)     ? 1     : x - 1;
  const int xp = (x == W - 1) ? W - 2 : x + 1;

  int off[9];
  off[0] = ym * W + xm; off[1] = ym * W + x; off[2] = ym * W + xp;
  off[3] = y  * W + xm; off[4] = y  * W + x; off[5] = y  * W + xp;
  off[6] = yp * W + xm; off[7] = yp * W + x; off[8] = yp * W + xp;
  const int ctr = y * W + x;

  const float* nb = nbr + ((size_t)b * C + cg * 8) * HW;
  const float* rb = ref + ((size_t)b * C + cg * 8) * HW;
  float*       ob = out + ((size_t)b * C + cg * 8) * HW;

  float v[8][9], r[8];
#pragma unroll
  for (int j = 0; j < 8; ++j) {
    r[j] = rb[j * HW + ctr];
#pragma unroll
    for (int k = 0; k < 9; ++k) v[j][k] = nb[j * HW + off[k]];
  }
  float sr = 0.f;
  float dot[9], ss[9];
#pragma unroll
  for (int k = 0; k < 9; ++k) { dot[k] = 0.f; ss[k] = 0.f; }
#pragma unroll
  for (int j = 0; j < 8; ++j) {
    sr = fmaf(r[j], r[j], sr);
#pragma unroll
    for (int k = 0; k < 9; ++k) {
      dot[k] = fmaf(r[j], v[j][k], dot[k]);
      ss[k]  = fmaf(v[j][k], v[j][k], ss[k]);
    }
  }
#pragma unroll
  for (int m = 8; m < 64; m <<= 1) {
    sr += __shfl_xor(sr, m);
#pragma unroll
    for (int k = 0; k < 9; ++k) {
      dot[k] += __shfl_xor(dot[k], m);
      ss[k]  += __shfl_xor(ss[k], m);
    }
  }
  const float invr = __frsqrt_rn(fmaxf(sr, 1e-24f));
  float d[9], invp[9];
  float mx = -INFINITY;
#pragma unroll
  for (int k = 0; k < 9; ++k) {
    invp[k] = __frsqrt_rn(fmaxf(ss[k], 1e-24f));
    d[k]    = dot[k] * invr * invp[k];
    mx      = fmaxf(mx, d[k]);
  }
  float s = 0.f;
  float coef[9];
#pragma unroll
  for (int k = 0; k < 9; ++k) {
    const float e = __expf(d[k] - mx);
    coef[k] = e;
    s += e;
  }
  const float sinv = 1.0f / s;
#pragma unroll
  for (int k = 0; k < 9; ++k) coef[k] *= sinv * invp[k];
#pragma unroll
  for (int j = 0; j < 8; ++j) {
    float a = 0.f;
#pragma unroll
    for (int k = 0; k < 9; ++k) a = fmaf(coef[k], v[j][k], a);
    const float diff = v[j][4] - r[j];
    const float wd   = __expf(-(diff * diff));
    ob[j * HW + ctr] = a * wd;
  }
}

extern "C" void kernel_launch(void* const* d_in, const int* in_sizes, int n_in,
                              void* d_out, int out_size, void* d_ws, size_t ws_size,
                              hipStream_t stream) {
  const float* nbr = (const float*)d_in[0];
  const float* ref = (const float*)d_in[1];
  float*       out = (float*)d_out;
  const size_t coef_bytes = (size_t)9 * PIX * sizeof(float);

  if (ws_size >= coef_bytes) {
    float* coef = (float*)d_ws;
    coef2_kernel<<<dim3(B * H), dim3(256), 0, stream>>>(nbr, ref, coef);   // 512 row-blocks
    apply_kernel<<<dim3(PIX / 4 * (C / 2) / 256), dim3(256), 0, stream>>>(nbr, ref, coef, out);
  } else {
    fused_nbr_attn<<<dim3(PIX / 32), dim3(256), 0, stream>>>(nbr, ref, out);
  }
}